// Round 14
// baseline (227.580 us; speedup 1.0000x reference)
//
#include <hip/hip_runtime.h>
#include <hip/hip_bf16.h>

typedef __attribute__((ext_vector_type(8))) short bf16x8;
typedef __attribute__((ext_vector_type(4))) float f32x4;
typedef __attribute__((ext_vector_type(4))) unsigned short u16x4;

#define MFMA16(a, b, c) __builtin_amdgcn_mfma_f32_16x16x32_bf16(a, b, c, 0, 0, 0)

// B=16, S=2048, EMB=512, HEAD_DIM=64
#define QSCALE 0.18033688011112042f

#define GLDS16(gp, lp)                                                         \
    __builtin_amdgcn_global_load_lds(                                          \
        (const __attribute__((address_space(1))) void*)(gp),                   \
        (__attribute__((address_space(3))) void*)(lp), 16, 0, 0)

__device__ __forceinline__ short nbf(float f) {
    __hip_bfloat16 h = __float2bfloat16(f);
    return *(short*)&h;
}
__device__ __forceinline__ unsigned short nbfu(float f) {
    __hip_bfloat16 h = __float2bfloat16(f);
    return *(unsigned short*)&h;
}

__global__ void wt_kernel(const float* __restrict__ Wq, const float* __restrict__ Wk,
                          const float* __restrict__ Wv, unsigned short* __restrict__ Wt) {
    const int h = blockIdx.x;
    const int mat = blockIdx.y;
    const int e = threadIdx.x;
    const float* W = (mat == 0) ? Wq : ((mat == 1) ? Wk : Wv);
    Wt[(mat * 64 + h) * 512 + e] = nbfu(W[e * 64 + h]);
}

// Fused QKV projection v4 (unchanged).
__global__ __launch_bounds__(512, 1) void qkv_proj(
    const float* __restrict__ x1, const unsigned short* __restrict__ Wt,
    unsigned short* __restrict__ Q, unsigned short* __restrict__ K,
    unsigned short* __restrict__ Vt)
{
    __shared__ char alds[2][16384];
    __shared__ char blds[2][12288];

    const int tid = threadIdx.x;
    const int W = tid >> 6, lane = tid & 63;
    const int c = lane & 15, g = lane >> 4;
    const int tokB = blockIdx.x * 128;

    const char* x1b = (const char*)x1;
    const char* Wtb = (const char*)Wt;

    const int tA0 = tid >> 3,           qA0 = (tid & 7) ^ (tA0 & 7);
    const int tA1 = (tid + 512) >> 3,   qA1 = (tid & 7) ^ (tA1 & 7);
    const size_t aoff0 = (size_t)(tokB + tA0) * 2048 + qA0 * 16;
    const size_t aoff1 = (size_t)(tokB + tA1) * 2048 + qA1 * 16;

    auto bsrc = [&](int j) -> size_t {
        const int n = j >> 6, c2 = (j >> 2) & 15, g2 = j & 3;
        return (size_t)((n >> 2) * 64 + (n & 3) * 16 + c2) * 1024 + g2 * 16;
    };
    const size_t boff0 = bsrc(tid), boff1 = bsrc(tid + 512);

    f32x4 acc[12];
#pragma unroll
    for (int n = 0; n < 12; ++n) acc[n] = (f32x4)0.f;

    GLDS16(x1b + aoff0, &alds[0][tid * 16]);
    GLDS16(x1b + aoff1, &alds[0][8192 + tid * 16]);
    GLDS16(Wtb + boff0, &blds[0][tid * 16]);
    if (tid < 256) GLDS16(Wtb + boff1, &blds[0][8192 + tid * 16]);

    const int arow = (W * 16 + c) * 128;
    const int aq0 = (((2 * g) ^ (c & 7)) * 16);
    const int aq1 = (((2 * g + 1) ^ (c & 7)) * 16);
    const int brd = (c * 4 + g) * 16;

    int buf = 0;
    for (int ks = 0; ks < 16; ++ks) {
        asm volatile("s_waitcnt vmcnt(0)\n\ts_barrier" ::: "memory");

        if (ks < 15) {
            const size_t ka = (size_t)(ks + 1) * 128;
            const size_t kb = (size_t)(ks + 1) * 64;
            char* ab = &alds[buf ^ 1][0];
            char* bb = &blds[buf ^ 1][0];
            GLDS16(x1b + aoff0 + ka, ab + tid * 16);
            GLDS16(x1b + aoff1 + ka, ab + 8192 + tid * 16);
            GLDS16(Wtb + boff0 + kb, bb + tid * 16);
            if (tid < 256) GLDS16(Wtb + boff1 + kb, bb + 8192 + tid * 16);
        }

        const char* ab = &alds[buf][0];
        const char* bb = &blds[buf][0];
        f32x4 a0 = *(const f32x4*)(ab + arow + aq0);
        f32x4 a1 = *(const f32x4*)(ab + arow + aq1);
        bf16x8 af;
        af[0] = nbf(a0[0]); af[1] = nbf(a0[1]); af[2] = nbf(a0[2]); af[3] = nbf(a0[3]);
        af[4] = nbf(a1[0]); af[5] = nbf(a1[1]); af[6] = nbf(a1[2]); af[7] = nbf(a1[3]);
#pragma unroll
        for (int n = 0; n < 12; ++n) {
            bf16x8 bf = *(const bf16x8*)(bb + n * 1024 + brd);
            acc[n] = MFMA16(af, bf, acc[n]);
        }
        buf ^= 1;
    }

    const int tok0 = tokB + W * 16;
#pragma unroll
    for (int n = 0; n < 4; ++n)
#pragma unroll
        for (int r = 0; r < 4; ++r)
            Q[(size_t)(tok0 + g * 4 + r) * 64 + n * 16 + c] = nbfu(acc[n][r] * QSCALE);
#pragma unroll
    for (int n = 0; n < 4; ++n)
#pragma unroll
        for (int r = 0; r < 4; ++r)
            K[(size_t)(tok0 + g * 4 + r) * 64 + n * 16 + c] = nbfu(acc[4 + n][r]);

    const int b = tok0 >> 11;
    const int sl = (tok0 & 2047) + g * 4;
#pragma unroll
    for (int n = 0; n < 4; ++n) {
        const int d = n * 16 + c;
        u16x4 pv;
#pragma unroll
        for (int r = 0; r < 4; ++r) pv[r] = nbfu(acc[8 + n][r]);
        *(u16x4*)(Vt + ((size_t)(b * 64 + d) << 11) + sl) = pv;
    }
}

// ---------------- common geometry macro for flash-family kernels ----------------
#define FA_PREAMBLE                                                                 \
    const int tid = threadIdx.x;                                                    \
    const int W = tid >> 6;                                                         \
    const int st = W >> 2;                                                          \
    const int w = W & 3;                                                            \
    const int lane = tid & 63;                                                      \
    const int c = lane & 15, g = lane >> 4;                                         \
    const int id = blockIdx.x;                                                      \
    const int b = 2 * (id & 7) + ((id >> 3) & 1);                                   \
    const int qt = 31 - (id >> 4);                                                  \
    const int n2 = (qt >> 1) + 1;                                                   \
    const int J = (n2 + 1) >> 1;                                                    \
    const int qr0c = qt * 64 + w * 16 + c;                                          \
    const size_t qrow_g = ((size_t)b << 11) + qt * 64 + w * 16;                     \
    const char* Kb = (const char*)(K + (((size_t)b << 11) * 64));                   \
    const char* Vb = (const char*)(Vt + (((size_t)b << 11) * 64));                  \
    const int c2 = tid & 15, g2 = (tid >> 4) & 3, nn = (tid >> 6) & 3,              \
              s4 = (tid >> 8) & 1;                                                  \
    const int koff = (nn * 16 + c2) * 128 + g2 * 16 + s4 * 64;                      \
    const int voff = (nn * 16 + c2) * 4096 + g2 * 16 + s4 * 64;

#define FA_STAGE_PAIR(dst, kbase, vbase)                                            \
    {                                                                               \
        char* d = (dst);                                                            \
        GLDS16((kbase) + koff,                 d + tid * 16);                       \
        GLDS16((kbase) + koff + 8192,          d + 8192 + tid * 16);                \
        GLDS16((vbase) + voff,                 d + 16384 + tid * 16);               \
        GLDS16((vbase) + voff + 128,           d + 16384 + 8192 + tid * 16);        \
        GLDS16((kbase) + 16384 + koff,         d + 32768 + tid * 16);               \
        GLDS16((kbase) + 16384 + koff + 8192,  d + 32768 + 8192 + tid * 16);        \
        GLDS16((vbase) + 256 + voff,           d + 49152 + tid * 16);               \
        GLDS16((vbase) + 256 + voff + 128,     d + 49152 + 8192 + tid * 16);        \
    }

// ---- PROBE 1: staging framework only (x4 repeats). dur/4 = A. ----
__global__ __launch_bounds__(512, 2) void fa_stage(
    const unsigned short* __restrict__ Q, const unsigned short* __restrict__ K,
    const unsigned short* __restrict__ Vt, float* __restrict__ out)
{
    __shared__ char kv[2][65536];
    __shared__ char p_lds[32768];
    FA_PREAMBLE
    (void)qr0c; (void)Q;
    if (tid == 0) p_lds[0] = 0;   // keep p_lds allocated (LDS parity with real kernel)

    for (int rep = 0; rep < 4; ++rep) {
        FA_STAGE_PAIR(&kv[0][0], Kb, Vb);
        for (int j = 0; j < J; ++j) {
            asm volatile("s_waitcnt vmcnt(0)\n\ts_barrier" ::: "memory");
            if (j + 1 < J) {
                const size_t kA = (size_t)(2 * j + 2) * 16384;
                const size_t vA = (size_t)(2 * j + 2) * 256;
                FA_STAGE_PAIR(&kv[(j & 1) ^ 1][0], Kb + kA, Vb + vA);
            }
        }
    }
    if (st == 0) out[(qrow_g + c) * 64 + g * 8] = (float)J + p_lds[1];
}

// ---- PROBE 2: full minus softmax (x2). dur/2 = A + QK + PV. ----
__global__ __launch_bounds__(512, 2) void fa_nosm(
    const unsigned short* __restrict__ Q, const unsigned short* __restrict__ K,
    const unsigned short* __restrict__ Vt, float* __restrict__ out)
{
    __shared__ char kv[2][65536];
    __shared__ char p_lds[32768];
    FA_PREAMBLE

    bf16x8 qf0 = *(const bf16x8*)(Q + (qrow_g + c) * 64 + g * 8);
    bf16x8 qf1 = *(const bf16x8*)(Q + (qrow_g + c) * 64 + 32 + g * 8);

    float l = 0.f;
    f32x4 acc[4];
#pragma unroll
    for (int n = 0; n < 4; ++n) acc[n] = (f32x4)0.f;

    for (int rep = 0; rep < 2; ++rep) {
        FA_STAGE_PAIR(&kv[0][0], Kb, Vb);
        for (int j = 0; j < J; ++j) {
            asm volatile("s_waitcnt vmcnt(0)\n\ts_barrier" ::: "memory");
            if (j + 1 < J) {
                const size_t kA = (size_t)(2 * j + 2) * 16384;
                const size_t vA = (size_t)(2 * j + 2) * 256;
                FA_STAGE_PAIR(&kv[(j & 1) ^ 1][0], Kb + kA, Vb + vA);
            }
            const int t = 2 * j + st;
            if (t < n2) {
                const char* kb = &kv[j & 1][st * 32768];
                const char* vb = kb + 16384;
                bf16x8 kfA[8], kfB[8];
#pragma unroll
                for (int h = 0; h < 2; ++h)
#pragma unroll
                    for (int n = 0; n < 4; ++n) {
                        kfA[h * 4 + n] = *(const bf16x8*)(kb + h * 8192 + n * 1024 + lane * 16);
                        kfB[h * 4 + n] = *(const bf16x8*)(kb + h * 8192 + 4096 + n * 1024 + lane * 16);
                    }
                f32x4 s[8];
#pragma unroll
                for (int i = 0; i < 8; ++i) s[i] = (f32x4)0.f;
                __builtin_amdgcn_s_setprio(1);
#pragma unroll
                for (int i = 0; i < 8; ++i) {
                    s[i] = MFMA16(kfA[i], qf0, s[i]);
                    s[i] = MFMA16(kfB[i], qf1, s[i]);
                }
                __builtin_amdgcn_s_setprio(0);

                // NO softmax: raw pack straight to P (s stays live), l = plain sum
                char* pw = &p_lds[W * 4096 + ((g >> 1) * 16 + c) * 16 + (g & 1) * 8];
#pragma unroll
                for (int h = 0; h < 2; ++h)
#pragma unroll
                    for (int n = 0; n < 4; ++n) {
                        const int i = h * 4 + n;
                        l += (s[i][0] + s[i][1]) + (s[i][2] + s[i][3]);
                        u16x4 pk;
                        pk[0] = nbfu(s[i][0]); pk[1] = nbfu(s[i][1]);
                        pk[2] = nbfu(s[i][2]); pk[3] = nbfu(s[i][3]);
                        *(u16x4*)(pw + (h * 2 + (n >> 1)) * 1024 + (n & 1) * 512) = pk;
                    }

                const char* pr = &p_lds[W * 4096 + lane * 16];
                bf16x8 pf[4];
#pragma unroll
                for (int ps = 0; ps < 4; ++ps) pf[ps] = *(const bf16x8*)(pr + ps * 1024);
                __builtin_amdgcn_s_setprio(1);
#pragma unroll
                for (int n = 0; n < 4; ++n)
#pragma unroll
                    for (int ps = 0; ps < 4; ++ps) {
                        bf16x8 vf = *(const bf16x8*)(vb + (ps >> 1) * 8192 + (ps & 1) * 4096 + n * 1024 + lane * 16);
                        acc[n] = MFMA16(pf[ps], vf, acc[n]);
                    }
                __builtin_amdgcn_s_setprio(0);
            }
        }
    }
    if (st == 0) {
#pragma unroll
        for (int n = 0; n < 4; ++n)
#pragma unroll
            for (int r = 0; r < 4; ++r)
                out[(qrow_g + g * 4 + r) * 64 + n * 16 + c] = acc[n][r] + l;
    } else {
#pragma unroll
        for (int n = 0; n < 4; ++n)
            asm volatile("" :: "v"(acc[n][0] + acc[n][1] + acc[n][2] + acc[n][3] + l));
    }
}

// ---- PROBE 3: full minus P-LDS + PV (x2). dur/2 = A + QK + SM. ----
__global__ __launch_bounds__(512, 2) void fa_nopv(
    const unsigned short* __restrict__ Q, const unsigned short* __restrict__ K,
    const unsigned short* __restrict__ Vt, float* __restrict__ out)
{
    __shared__ char kv[2][65536];
    __shared__ char p_lds[32768];
    FA_PREAMBLE
    if (tid == 0) p_lds[0] = 0;

    bf16x8 qf0 = *(const bf16x8*)(Q + (qrow_g + c) * 64 + g * 8);
    bf16x8 qf1 = *(const bf16x8*)(Q + (qrow_g + c) * 64 + 32 + g * 8);

    float m = -1e30f, l = 0.f;
    f32x4 acc[4];
#pragma unroll
    for (int n = 0; n < 4; ++n) acc[n] = (f32x4)0.f;

    for (int rep = 0; rep < 2; ++rep) {
        FA_STAGE_PAIR(&kv[0][0], Kb, Vb);
        for (int j = 0; j < J; ++j) {
            asm volatile("s_waitcnt vmcnt(0)\n\ts_barrier" ::: "memory");
            if (j + 1 < J) {
                const size_t kA = (size_t)(2 * j + 2) * 16384;
                const size_t vA = (size_t)(2 * j + 2) * 256;
                FA_STAGE_PAIR(&kv[(j & 1) ^ 1][0], Kb + kA, Vb + vA);
            }
            const int t = 2 * j + st;
            if (t < n2) {
                const char* kb = &kv[j & 1][st * 32768];
                bf16x8 kfA[8], kfB[8];
#pragma unroll
                for (int h = 0; h < 2; ++h)
#pragma unroll
                    for (int n = 0; n < 4; ++n) {
                        kfA[h * 4 + n] = *(const bf16x8*)(kb + h * 8192 + n * 1024 + lane * 16);
                        kfB[h * 4 + n] = *(const bf16x8*)(kb + h * 8192 + 4096 + n * 1024 + lane * 16);
                    }
                f32x4 s[8];
#pragma unroll
                for (int i = 0; i < 8; ++i) s[i] = (f32x4)0.f;
                __builtin_amdgcn_s_setprio(1);
#pragma unroll
                for (int i = 0; i < 8; ++i) {
                    s[i] = MFMA16(kfA[i], qf0, s[i]);
                    s[i] = MFMA16(kfB[i], qf1, s[i]);
                }
                __builtin_amdgcn_s_setprio(0);

                if (t == n2 - 1) {
#pragma unroll
                    for (int h = 0; h < 2; ++h)
#pragma unroll
                        for (int n = 0; n < 4; ++n) {
                            const int key0 = t * 128 + h * 64 + n * 16 + g * 4;
#pragma unroll
                            for (int r = 0; r < 4; ++r)
                                if (key0 + r > qr0c) s[h * 4 + n][r] = -1e30f;
                        }
                }

                float tm = -1e30f;
#pragma unroll
                for (int i = 0; i < 8; ++i)
                    tm = fmaxf(tm, fmaxf(fmaxf(s[i][0], s[i][1]), fmaxf(s[i][2], s[i][3])));
                if (__any(tm > m + 8.f)) {
                    float gm = tm;
                    gm = fmaxf(gm, __shfl_xor(gm, 16, 64));
                    gm = fmaxf(gm, __shfl_xor(gm, 32, 64));
                    const float mn = fmaxf(m, gm);
                    const float alpha = exp2f(m - mn);
                    m = mn;
                    l *= alpha;
                    float al[4];
#pragma unroll
                    for (int r = 0; r < 4; ++r) al[r] = __shfl(alpha, g * 4 + r, 16);
#pragma unroll
                    for (int n = 0; n < 4; ++n)
#pragma unroll
                        for (int r = 0; r < 4; ++r) acc[n][r] *= al[r];
                }
#pragma unroll
                for (int h = 0; h < 2; ++h)
#pragma unroll
                    for (int n = 0; n < 4; ++n) {
                        const int i = h * 4 + n;
                        float p0 = exp2f(s[i][0] - m);
                        float p1 = exp2f(s[i][1] - m);
                        float p2 = exp2f(s[i][2] - m);
                        float p3 = exp2f(s[i][3] - m);
                        l += (p0 + p1) + (p2 + p3);
                        u16x4 pk;
                        pk[0] = nbfu(p0); pk[1] = nbfu(p1); pk[2] = nbfu(p2); pk[3] = nbfu(p3);
                        asm volatile("" :: "v"(*(const unsigned long long*)&pk));  // keepalive, no P write / PV
                    }
            }
        }
    }
    if (st == 0) {
#pragma unroll
        for (int n = 0; n < 4; ++n)
#pragma unroll
            for (int r = 0; r < 4; ++r)
                out[(qrow_g + g * 4 + r) * 64 + n * 16 + c] = acc[n][r] + l + m;
    } else {
        asm volatile("" :: "v"(l + m));
    }
}

// ---- REAL kernel: v9 (R11, known-good 40.0us), runs LAST -> correct d_out ----
__global__ __launch_bounds__(512, 2) void flash_attn(
    const unsigned short* __restrict__ Q, const unsigned short* __restrict__ K,
    const unsigned short* __restrict__ Vt, float* __restrict__ out)
{
    __shared__ char kv[2][65536];
    __shared__ char p_lds[32768];
    FA_PREAMBLE

    bf16x8 qf0 = *(const bf16x8*)(Q + (qrow_g + c) * 64 + g * 8);
    bf16x8 qf1 = *(const bf16x8*)(Q + (qrow_g + c) * 64 + 32 + g * 8);

    float m = -1e30f, l = 0.f;
    f32x4 acc[4];
#pragma unroll
    for (int n = 0; n < 4; ++n) acc[n] = (f32x4)0.f;

    FA_STAGE_PAIR(&kv[0][0], Kb, Vb);

    for (int j = 0; j < J; ++j) {
        asm volatile("s_waitcnt vmcnt(0)\n\ts_barrier" ::: "memory");

        if (j + 1 < J) {
            const size_t kA = (size_t)(2 * j + 2) * 16384;
            const size_t vA = (size_t)(2 * j + 2) * 256;
            FA_STAGE_PAIR(&kv[(j & 1) ^ 1][0], Kb + kA, Vb + vA);
        }

        const int t = 2 * j + st;
        if (t < n2) {
            const char* kb = &kv[j & 1][st * 32768];
            const char* vb = kb + 16384;

            bf16x8 kfA[8], kfB[8];
#pragma unroll
            for (int h = 0; h < 2; ++h)
#pragma unroll
                for (int n = 0; n < 4; ++n) {
                    kfA[h * 4 + n] = *(const bf16x8*)(kb + h * 8192 + n * 1024 + lane * 16);
                    kfB[h * 4 + n] = *(const bf16x8*)(kb + h * 8192 + 4096 + n * 1024 + lane * 16);
                }
            f32x4 s[8];
#pragma unroll
            for (int i = 0; i < 8; ++i) s[i] = (f32x4)0.f;
            __builtin_amdgcn_s_setprio(1);
#pragma unroll
            for (int i = 0; i < 8; ++i) {
                s[i] = MFMA16(kfA[i], qf0, s[i]);
                s[i] = MFMA16(kfB[i], qf1, s[i]);
            }
            __builtin_amdgcn_s_setprio(0);

            if (t == n2 - 1) {
#pragma unroll
                for (int h = 0; h < 2; ++h)
#pragma unroll
                    for (int n = 0; n < 4; ++n) {
                        const int key0 = t * 128 + h * 64 + n * 16 + g * 4;
#pragma unroll
                        for (int r = 0; r < 4; ++r)
                            if (key0 + r > qr0c) s[h * 4 + n][r] = -1e30f;
                    }
            }

            float tm = -1e30f;
#pragma unroll
            for (int i = 0; i < 8; ++i)
                tm = fmaxf(tm, fmaxf(fmaxf(s[i][0], s[i][1]), fmaxf(s[i][2], s[i][3])));

            if (__any(tm > m + 8.f)) {
                float gm = tm;
                gm = fmaxf(gm, __shfl_xor(gm, 16, 64));
                gm = fmaxf(gm, __shfl_xor(gm, 32, 64));
                const float mn = fmaxf(m, gm);
                const float alpha = exp2f(m - mn);
                m = mn;
                l *= alpha;
                float al[4];
#pragma unroll
                for (int r = 0; r < 4; ++r) al[r] = __shfl(alpha, g * 4 + r, 16);
#pragma unroll
                for (int n = 0; n < 4; ++n)
#pragma unroll
                    for (int r = 0; r < 4; ++r) acc[n][r] *= al[r];
            }

            char* pw = &p_lds[W * 4096 + ((g >> 1) * 16 + c) * 16 + (g & 1) * 8];
#pragma unroll
            for (int h = 0; h < 2; ++h)
#pragma unroll
                for (int n = 0; n < 4; ++n) {
                    const int i = h * 4 + n;
                    float p0 = exp2f(s[i][0] - m);
                    float p1 = exp2f(s[i][1] - m);
                    float p2 = exp2f(s[i][2] - m);
                    float p3 = exp2f(s[i][3] - m);
                    l += (p0 + p1) + (p2 + p3);
                    u16x4 pk;
                    pk[0] = nbfu(p0); pk[1] = nbfu(p1); pk[2] = nbfu(p2); pk[3] = nbfu(p3);
                    *(u16x4*)(pw + (h * 2 + (n >> 1)) * 1024 + (n & 1) * 512) = pk;
                }

            const char* pr = &p_lds[W * 4096 + lane * 16];
            bf16x8 pf[4];
#pragma unroll
            for (int ps = 0; ps < 4; ++ps) pf[ps] = *(const bf16x8*)(pr + ps * 1024);

            __builtin_amdgcn_s_setprio(1);
#pragma unroll
            for (int n = 0; n < 4; ++n)
#pragma unroll
                for (int ps = 0; ps < 4; ++ps) {
                    bf16x8 vf = *(const bf16x8*)(vb + (ps >> 1) * 8192 + (ps & 1) * 4096 + n * 1024 + lane * 16);
                    acc[n] = MFMA16(pf[ps], vf, acc[n]);
                }
            __builtin_amdgcn_s_setprio(0);
        }
    }

    __syncthreads();
    float* accb = (float*)&kv[0][0];
    float* mb = (float*)&kv[0][16384];
    float* lb = (float*)&kv[0][16384 + 256];

    if (st == 1) {
        l += __shfl_xor(l, 16, 64);
        l += __shfl_xor(l, 32, 64);
        if (g == 0) { mb[w * 16 + c] = m; lb[w * 16 + c] = l; }
#pragma unroll
        for (int n = 0; n < 4; ++n)
#pragma unroll
            for (int r = 0; r < 4; ++r)
                accb[w * 1024 + (g * 4 + r) * 64 + n * 16 + c] = acc[n][r];
    }
    __syncthreads();

    if (st == 0) {
        l += __shfl_xor(l, 16, 64);
        l += __shfl_xor(l, 32, 64);
        const float m1c = mb[w * 16 + c];
        const float l1c = lb[w * 16 + c];
        const float mF = fmaxf(m, m1c);
        const float a0 = exp2f(m - mF);
        const float a1 = (m1c > -1e29f) ? exp2f(m1c - mF) : 0.f;
        const float inv = 1.f / (l * a0 + l1c * a1);
        const float s0 = a0 * inv, s1 = a1 * inv;
        float s0r[4], s1r[4];
#pragma unroll
        for (int r = 0; r < 4; ++r) {
            s0r[r] = __shfl(s0, g * 4 + r, 16);
            s1r[r] = __shfl(s1, g * 4 + r, 16);
        }
#pragma unroll
        for (int n = 0; n < 4; ++n)
#pragma unroll
            for (int r = 0; r < 4; ++r) {
                const float a1v = accb[w * 1024 + (g * 4 + r) * 64 + n * 16 + c];
                out[(qrow_g + g * 4 + r) * 64 + n * 16 + c] = acc[n][r] * s0r[r] + a1v * s1r[r];
            }
    }
}

extern "C" void kernel_launch(void* const* d_in, const int* in_sizes, int n_in,
                              void* d_out, int out_size, void* d_ws, size_t ws_size,
                              hipStream_t stream) {
    const float* x1 = (const float*)d_in[0];
    const float* Wq = (const float*)d_in[2];
    const float* Wk = (const float*)d_in[3];
    const float* Wv = (const float*)d_in[4];
    float* out = (float*)d_out;

    unsigned short* Wt  = (unsigned short*)d_ws;
    unsigned short* Qw  = (unsigned short*)((char*)d_ws + 196608);
    unsigned short* Kw  = (unsigned short*)((char*)d_ws + 196608 + 4194304);
    unsigned short* Vtw = (unsigned short*)((char*)d_ws + 196608 + 2 * 4194304);

    wt_kernel<<<dim3(64, 3), 512, 0, stream>>>(Wq, Wk, Wv, Wt);
    qkv_proj<<<256, 512, 0, stream>>>(x1, Wt, Qw, Kw, Vtw);
    // ---- ablation probes (write garbage to d_out; real flash overwrites) ----
    fa_stage<<<512, 512, 0, stream>>>(Qw, Kw, Vtw, out);
    fa_nosm<<<512, 512, 0, stream>>>(Qw, Kw, Vtw, out);
    fa_nopv<<<512, 512, 0, stream>>>(Qw, Kw, Vtw, out);
    // ---- real kernel, LAST ----
    flash_attn<<<512, 512, 0, stream>>>(Qw, Kw, Vtw, out);
}

// Round 15
// 57.928 us; speedup vs baseline: 3.9287x; 3.9287x over previous
//
#include <hip/hip_runtime.h>
#include <hip/hip_bf16.h>

typedef __attribute__((ext_vector_type(8))) short bf16x8;
typedef __attribute__((ext_vector_type(4))) float f32x4;
typedef __attribute__((ext_vector_type(4))) unsigned short u16x4;

#define MFMA16(a, b, c) __builtin_amdgcn_mfma_f32_16x16x32_bf16(a, b, c, 0, 0, 0)

// B=16, S=2048, EMB=512, HEAD_DIM=64
// Q pre-scaled by 0.125 * log2(e): softmax runs in exp2 domain.
#define QSCALE 0.18033688011112042f

#define GLDS16(gp, lp)                                                         \
    __builtin_amdgcn_global_load_lds(                                          \
        (const __attribute__((address_space(1))) void*)(gp),                   \
        (__attribute__((address_space(3))) void*)(lp), 16, 0, 0)

__device__ __forceinline__ short nbf(float f) {
    __hip_bfloat16 h = __float2bfloat16(f);
    return *(short*)&h;
}
__device__ __forceinline__ unsigned short nbfu(float f) {
    __hip_bfloat16 h = __float2bfloat16(f);
    return *(unsigned short*)&h;
}

__global__ void wt_kernel(const float* __restrict__ Wq, const float* __restrict__ Wk,
                          const float* __restrict__ Wv, unsigned short* __restrict__ Wt) {
    const int h = blockIdx.x;
    const int mat = blockIdx.y;
    const int e = threadIdx.x;
    const float* W = (mat == 0) ? Wq : ((mat == 1) ? Wk : Wv);
    Wt[(mat * 64 + h) * 512 + e] = nbfu(W[e * 64 + h]);
}

// Fused QKV projection v5: K and V written in FRAGMENT-TILED global layouts so
// flash staging is a pure linear copy.
//   Kf[b][ht][dh][n][c][g]x8bf16 at ushort idx b*131072 + ht*4096 + dh*2048 +
//       n*512 + (g*16+c)*8 + j  = K[key ht*64+n*16+c][d dh*32+g*8+j]
//   Vf[b][ht][sub][n][c][g]x8bf16 (same strides) = v[s ht*64+sub*32+g*8+j][d n*16+c]
__global__ __launch_bounds__(512, 1) void qkv_proj(
    const float* __restrict__ x1, const unsigned short* __restrict__ Wt,
    unsigned short* __restrict__ Q, unsigned short* __restrict__ Kf,
    unsigned short* __restrict__ Vf)
{
    __shared__ char alds[2][16384];
    __shared__ char blds[2][12288];

    const int tid = threadIdx.x;
    const int W = tid >> 6, lane = tid & 63;
    const int c = lane & 15, g = lane >> 4;
    const int tokB = blockIdx.x * 128;

    const char* x1b = (const char*)x1;
    const char* Wtb = (const char*)Wt;

    const int tA0 = tid >> 3,           qA0 = (tid & 7) ^ (tA0 & 7);
    const int tA1 = (tid + 512) >> 3,   qA1 = (tid & 7) ^ (tA1 & 7);
    const size_t aoff0 = (size_t)(tokB + tA0) * 2048 + qA0 * 16;
    const size_t aoff1 = (size_t)(tokB + tA1) * 2048 + qA1 * 16;

    auto bsrc = [&](int j) -> size_t {
        const int n = j >> 6, c2 = (j >> 2) & 15, g2 = j & 3;
        return (size_t)((n >> 2) * 64 + (n & 3) * 16 + c2) * 1024 + g2 * 16;
    };
    const size_t boff0 = bsrc(tid), boff1 = bsrc(tid + 512);

    f32x4 acc[12];
#pragma unroll
    for (int n = 0; n < 12; ++n) acc[n] = (f32x4)0.f;

    GLDS16(x1b + aoff0, &alds[0][tid * 16]);
    GLDS16(x1b + aoff1, &alds[0][8192 + tid * 16]);
    GLDS16(Wtb + boff0, &blds[0][tid * 16]);
    if (tid < 256) GLDS16(Wtb + boff1, &blds[0][8192 + tid * 16]);

    const int arow = (W * 16 + c) * 128;
    const int aq0 = (((2 * g) ^ (c & 7)) * 16);
    const int aq1 = (((2 * g + 1) ^ (c & 7)) * 16);
    const int brd = (c * 4 + g) * 16;

    int buf = 0;
    for (int ks = 0; ks < 16; ++ks) {
        asm volatile("s_waitcnt vmcnt(0)\n\ts_barrier" ::: "memory");

        if (ks < 15) {
            const size_t ka = (size_t)(ks + 1) * 128;
            const size_t kb = (size_t)(ks + 1) * 64;
            char* ab = &alds[buf ^ 1][0];
            char* bb = &blds[buf ^ 1][0];
            GLDS16(x1b + aoff0 + ka, ab + tid * 16);
            GLDS16(x1b + aoff1 + ka, ab + 8192 + tid * 16);
            GLDS16(Wtb + boff0 + kb, bb + tid * 16);
            if (tid < 256) GLDS16(Wtb + boff1 + kb, bb + 8192 + tid * 16);
        }

        const char* ab = &alds[buf][0];
        const char* bb = &blds[buf][0];
        f32x4 a0 = *(const f32x4*)(ab + arow + aq0);
        f32x4 a1 = *(const f32x4*)(ab + arow + aq1);
        bf16x8 af;
        af[0] = nbf(a0[0]); af[1] = nbf(a0[1]); af[2] = nbf(a0[2]); af[3] = nbf(a0[3]);
        af[4] = nbf(a1[0]); af[5] = nbf(a1[1]); af[6] = nbf(a1[2]); af[7] = nbf(a1[3]);
#pragma unroll
        for (int n = 0; n < 12; ++n) {
            bf16x8 bf = *(const bf16x8*)(bb + n * 1024 + brd);
            acc[n] = MFMA16(af, bf, acc[n]);
        }
        buf ^= 1;
    }

    const int tok0 = tokB + W * 16;
    const int bb2 = tokB >> 11;                          // batch
    const int ht = ((tokB & 2047) >> 6) + (W >> 2);      // 64-key half-tile

    // ---- Q: row-major, pre-scaled (unchanged) ----
#pragma unroll
    for (int n = 0; n < 4; ++n)
#pragma unroll
        for (int r = 0; r < 4; ++r)
            Q[(size_t)(tok0 + g * 4 + r) * 64 + n * 16 + c] = nbfu(acc[n][r] * QSCALE);

    // ---- K -> Kf fragment-tiled ----
    {
        unsigned short* kf = Kf + (size_t)bb2 * 131072 + (size_t)ht * 4096;
#pragma unroll
        for (int n = 0; n < 4; ++n) {
            const int gf = (n & 1) * 2 + (c >> 3);
            const size_t base = (size_t)(n >> 1) * 2048 + (W & 3) * 512 + (c & 7);
#pragma unroll
            for (int r = 0; r < 4; ++r)
                kf[base + (size_t)(gf * 16 + g * 4 + r) * 8] = nbfu(acc[4 + n][r]);
        }
    }

    // ---- V -> Vf fragment-tiled (8B vector stores, r contiguous) ----
    {
        unsigned short* vf = Vf + (size_t)bb2 * 131072 + (size_t)ht * 4096;
        const int sub = (W & 3) >> 1;
        const int gf = (W & 1) * 2 + (g >> 1);
        const int jb = (g & 1) * 4;
#pragma unroll
        for (int n = 0; n < 4; ++n) {
            u16x4 pv;
#pragma unroll
            for (int r = 0; r < 4; ++r) pv[r] = nbfu(acc[8 + n][r]);
            *(u16x4*)(vf + (size_t)sub * 2048 + n * 512 + (gf * 16 + c) * 8 + jb) = pv;
        }
    }
}

// Causal flash attention v11: v9 compute body + LINEAR staging from the
// fragment-tiled Kf/Vf global layouts. Each wave's GLDS reads 1KB contiguous
// (was 64B chunks at 128B/4KB strides -> the R14-ablated 18.7us staging cost).
__global__ __launch_bounds__(512, 2) void flash_attn(
    const unsigned short* __restrict__ Q, const unsigned short* __restrict__ Kf,
    const unsigned short* __restrict__ Vf, float* __restrict__ out)
{
    __shared__ char kv[2][65536];   // [buf][ K0 16K | V0 16K | K1 16K | V1 16K ]
    __shared__ char p_lds[32768];   // [wave 0..7][ps=4][lane=64]x16B

    const int tid = threadIdx.x;
    const int W = tid >> 6;
    const int st = W >> 2;
    const int w = W & 3;
    const int lane = tid & 63;
    const int c = lane & 15, g = lane >> 4;

    const int id = blockIdx.x;
    const int b = 2 * (id & 7) + ((id >> 3) & 1);
    const int qt = 31 - (id >> 4);            // heavy blocks dispatch first
    const int n2 = (qt >> 1) + 1;             // # 128-key tiles
    const int J = (n2 + 1) >> 1;              // super-iterations (tile pairs)
    const int qr0c = qt * 64 + w * 16 + c;
    const size_t qrow_g = ((size_t)b << 11) + qt * 64 + w * 16;

    bf16x8 qf0 = *(const bf16x8*)(Q + (qrow_g + c) * 64 + g * 8);
    bf16x8 qf1 = *(const bf16x8*)(Q + (qrow_g + c) * 64 + 32 + g * 8);

    const char* Kfb = (const char*)(Kf + (size_t)b * 131072);  // 256KB/batch
    const char* Vfb = (const char*)(Vf + (size_t)b * 131072);

    const int off0 = tid * 16, off1 = (tid + 512) * 16;

    float m = -1e30f, l = 0.f;
    f32x4 acc[4];
#pragma unroll
    for (int n = 0; n < 4; ++n) acc[n] = (f32x4)0.f;

    auto STAGE = [&](int p, char* d) {   // stage tile pair (2p, 2p+1), all linear
        const size_t o0 = (size_t)(2 * p) * 16384;
        const size_t o1 = o0 + 16384;
        GLDS16(Kfb + o0 + off0, d + off0);
        GLDS16(Kfb + o0 + off1, d + off1);
        GLDS16(Vfb + o0 + off0, d + 16384 + off0);
        GLDS16(Vfb + o0 + off1, d + 16384 + off1);
        GLDS16(Kfb + o1 + off0, d + 32768 + off0);
        GLDS16(Kfb + o1 + off1, d + 32768 + off1);
        GLDS16(Vfb + o1 + off0, d + 49152 + off0);
        GLDS16(Vfb + o1 + off1, d + 49152 + off1);
    };

    STAGE(0, &kv[0][0]);

    for (int j = 0; j < J; ++j) {
        asm volatile("s_waitcnt vmcnt(0)\n\ts_barrier" ::: "memory");

        if (j + 1 < J) STAGE(j + 1, &kv[(j & 1) ^ 1][0]);

        const int t = 2 * j + st;
        if (t < n2) {
            const char* kb = &kv[j & 1][st * 32768];
            const char* vb = kb + 16384;

            bf16x8 kfA[8], kfB[8];
#pragma unroll
            for (int h = 0; h < 2; ++h)
#pragma unroll
                for (int n = 0; n < 4; ++n) {
                    kfA[h * 4 + n] = *(const bf16x8*)(kb + h * 8192 + n * 1024 + lane * 16);
                    kfB[h * 4 + n] = *(const bf16x8*)(kb + h * 8192 + 4096 + n * 1024 + lane * 16);
                }
            f32x4 s[8];
#pragma unroll
            for (int i = 0; i < 8; ++i) s[i] = (f32x4)0.f;
            __builtin_amdgcn_s_setprio(1);
#pragma unroll
            for (int i = 0; i < 8; ++i) {
                s[i] = MFMA16(kfA[i], qf0, s[i]);
                s[i] = MFMA16(kfB[i], qf1, s[i]);
            }
            __builtin_amdgcn_s_setprio(0);

            if (t == n2 - 1) {
#pragma unroll
                for (int h = 0; h < 2; ++h)
#pragma unroll
                    for (int n = 0; n < 4; ++n) {
                        const int key0 = t * 128 + h * 64 + n * 16 + g * 4;
#pragma unroll
                        for (int r = 0; r < 4; ++r)
                            if (key0 + r > qr0c) s[h * 4 + n][r] = -1e30f;
                    }
            }

            float tm = -1e30f;
#pragma unroll
            for (int i = 0; i < 8; ++i)
                tm = fmaxf(tm, fmaxf(fmaxf(s[i][0], s[i][1]), fmaxf(s[i][2], s[i][3])));

            if (__any(tm > m + 8.f)) {
                float gm = tm;
                gm = fmaxf(gm, __shfl_xor(gm, 16, 64));
                gm = fmaxf(gm, __shfl_xor(gm, 32, 64));
                const float mn = fmaxf(m, gm);
                const float alpha = exp2f(m - mn);
                m = mn;
                l *= alpha;
                float al[4];
#pragma unroll
                for (int r = 0; r < 4; ++r) al[r] = __shfl(alpha, g * 4 + r, 16);
#pragma unroll
                for (int n = 0; n < 4; ++n)
#pragma unroll
                    for (int r = 0; r < 4; ++r) acc[n][r] *= al[r];
            }

            char* pw = &p_lds[W * 4096 + ((g >> 1) * 16 + c) * 16 + (g & 1) * 8];
#pragma unroll
            for (int h = 0; h < 2; ++h)
#pragma unroll
                for (int n = 0; n < 4; ++n) {
                    const int i = h * 4 + n;
                    float p0 = exp2f(s[i][0] - m);
                    float p1 = exp2f(s[i][1] - m);
                    float p2 = exp2f(s[i][2] - m);
                    float p3 = exp2f(s[i][3] - m);
                    l += (p0 + p1) + (p2 + p3);
                    u16x4 pk;
                    pk[0] = nbfu(p0); pk[1] = nbfu(p1); pk[2] = nbfu(p2); pk[3] = nbfu(p3);
                    *(u16x4*)(pw + (h * 2 + (n >> 1)) * 1024 + (n & 1) * 512) = pk;
                }

            const char* pr = &p_lds[W * 4096 + lane * 16];
            bf16x8 pf[4];
#pragma unroll
            for (int ps = 0; ps < 4; ++ps) pf[ps] = *(const bf16x8*)(pr + ps * 1024);

            __builtin_amdgcn_s_setprio(1);
#pragma unroll
            for (int n = 0; n < 4; ++n)
#pragma unroll
                for (int ps = 0; ps < 4; ++ps) {
                    bf16x8 vf = *(const bf16x8*)(vb + (ps >> 1) * 8192 + (ps & 1) * 4096 + n * 1024 + lane * 16);
                    acc[n] = MFMA16(pf[ps], vf, acc[n]);
                }
            __builtin_amdgcn_s_setprio(0);
        }
    }

    // ---- epilogue: merge set 1 into set 0 via LDS ----
    __syncthreads();
    float* accb = (float*)&kv[0][0];
    float* mb = (float*)&kv[0][16384];
    float* lb = (float*)&kv[0][16384 + 256];

    if (st == 1) {
        l += __shfl_xor(l, 16, 64);
        l += __shfl_xor(l, 32, 64);
        if (g == 0) { mb[w * 16 + c] = m; lb[w * 16 + c] = l; }
#pragma unroll
        for (int n = 0; n < 4; ++n)
#pragma unroll
            for (int r = 0; r < 4; ++r)
                accb[w * 1024 + (g * 4 + r) * 64 + n * 16 + c] = acc[n][r];
    }
    __syncthreads();

    if (st == 0) {
        l += __shfl_xor(l, 16, 64);
        l += __shfl_xor(l, 32, 64);
        const float m1c = mb[w * 16 + c];
        const float l1c = lb[w * 16 + c];
        const float mF = fmaxf(m, m1c);
        const float a0 = exp2f(m - mF);
        const float a1 = (m1c > -1e29f) ? exp2f(m1c - mF) : 0.f;
        const float inv = 1.f / (l * a0 + l1c * a1);
        const float s0 = a0 * inv, s1 = a1 * inv;
        float s0r[4], s1r[4];
#pragma unroll
        for (int r = 0; r < 4; ++r) {
            s0r[r] = __shfl(s0, g * 4 + r, 16);
            s1r[r] = __shfl(s1, g * 4 + r, 16);
        }
#pragma unroll
        for (int n = 0; n < 4; ++n)
#pragma unroll
            for (int r = 0; r < 4; ++r) {
                const float a1v = accb[w * 1024 + (g * 4 + r) * 64 + n * 16 + c];
                out[(qrow_g + g * 4 + r) * 64 + n * 16 + c] = acc[n][r] * s0r[r] + a1v * s1r[r];
            }
    }
}

extern "C" void kernel_launch(void* const* d_in, const int* in_sizes, int n_in,
                              void* d_out, int out_size, void* d_ws, size_t ws_size,
                              hipStream_t stream) {
    const float* x1 = (const float*)d_in[0];
    const float* Wq = (const float*)d_in[2];
    const float* Wk = (const float*)d_in[3];
    const float* Wv = (const float*)d_in[4];
    float* out = (float*)d_out;

    unsigned short* Wt  = (unsigned short*)d_ws;
    unsigned short* Qw  = (unsigned short*)((char*)d_ws + 196608);
    unsigned short* Kfw = (unsigned short*)((char*)d_ws + 196608 + 4194304);
    unsigned short* Vfw = (unsigned short*)((char*)d_ws + 196608 + 2 * 4194304);

    wt_kernel<<<dim3(64, 3), 512, 0, stream>>>(Wq, Wk, Wv, Wt);
    qkv_proj<<<256, 512, 0, stream>>>(x1, Wt, Qw, Kfw, Vfw);
    flash_attn<<<512, 512, 0, stream>>>(Qw, Kfw, Vfw, out);
}